// Round 2
// baseline (564.872 us; speedup 1.0000x reference)
//
#include <hip/hip_runtime.h>

namespace {

constexpr int kHidden = 1024;
constexpr int kGrid   = 512;
constexpr int kB = 4;
constexpr int kE = 256;
constexpr int kD = 128;

// gaussian kernel, KSIZE=3, SIGMA=1: g = [e^-.5, 1, e^-.5]/sum
constexpr float kG0   = 0.27406862f;   // edge taps
constexpr float kG1   = 0.45186276f;   // center tap
constexpr float kEdge = kG0 + kG1;     // boundary weight-sum (zero padding)

constexpr int BM = 64, BN = 64, BK = 16;

// C[M][N] = (A[M][K] @ W[N][K]^T + bias) * rowmask, A row-major lda=K,
// W rows at stride ldw. Requires M%64==0, N%64==0, K%16==0.
__global__ __launch_bounds__(256)
void gemm_nt(const float* __restrict__ A, const float* __restrict__ W,
             const float* __restrict__ bias, const float* __restrict__ rowmask,
             float* __restrict__ C, int K, int ldw, int N) {
  __shared__ float As[BK][BM + 4];
  __shared__ float Ws[BK][BN + 4];
  const int tid = threadIdx.x;
  const int tx = tid & 15, ty = tid >> 4;
  const int row0 = blockIdx.y * BM, col0 = blockIdx.x * BN;
  const int lr = tid >> 2;          // 0..63 tile row (or W row)
  const int lk = (tid & 3) << 2;    // 0,4,8,12 k-offset
  const float* Ap = A + (size_t)(row0 + lr) * K + lk;
  const float* Wp = W + (size_t)(col0 + lr) * ldw + lk;
  float acc[4][4] = {};

  for (int k0 = 0; k0 < K; k0 += BK) {
    const float4 a4 = *(const float4*)(Ap + k0);
    const float4 w4 = *(const float4*)(Wp + k0);
    __syncthreads();
    As[lk + 0][lr] = a4.x; As[lk + 1][lr] = a4.y;
    As[lk + 2][lr] = a4.z; As[lk + 3][lr] = a4.w;
    Ws[lk + 0][lr] = w4.x; Ws[lk + 1][lr] = w4.y;
    Ws[lk + 2][lr] = w4.z; Ws[lk + 3][lr] = w4.w;
    __syncthreads();
#pragma unroll
    for (int kk = 0; kk < BK; ++kk) {
      const float4 av = *(const float4*)&As[kk][ty << 2];
      const float4 wv = *(const float4*)&Ws[kk][tx << 2];
      acc[0][0] += av.x * wv.x; acc[0][1] += av.x * wv.y;
      acc[0][2] += av.x * wv.z; acc[0][3] += av.x * wv.w;
      acc[1][0] += av.y * wv.x; acc[1][1] += av.y * wv.y;
      acc[1][2] += av.y * wv.z; acc[1][3] += av.y * wv.w;
      acc[2][0] += av.z * wv.x; acc[2][1] += av.z * wv.y;
      acc[2][2] += av.z * wv.z; acc[2][3] += av.z * wv.w;
      acc[3][0] += av.w * wv.x; acc[3][1] += av.w * wv.y;
      acc[3][2] += av.w * wv.z; acc[3][3] += av.w * wv.w;
    }
  }

  float4 b4 = make_float4(0.f, 0.f, 0.f, 0.f);
  if (bias) b4 = *(const float4*)(bias + col0 + (tx << 2));
#pragma unroll
  for (int i = 0; i < 4; ++i) {
    const int r = row0 + (ty << 2) + i;
    const float rm = rowmask ? rowmask[r] : 1.f;
    float4 o;
    o.x = (acc[i][0] + b4.x) * rm;
    o.y = (acc[i][1] + b4.y) * rm;
    o.z = (acc[i][2] + b4.z) * rm;
    o.w = (acc[i][3] + b4.w) * rm;
    *(float4*)(C + (size_t)r * N + col0 + (tx << 2)) = o;
  }
}

// grid[b,d,e,o] = dec_term[b,d,o] + enc_term[b,e,o] + b_fus[o]
// blockIdx.x = (b*kD+d), blockIdx.y = e-chunk of 64 rows.
// 256 threads cover 2 e-rows x 128 float4 per iter, 32 iters.
__global__ __launch_bounds__(256)
void assemble(const float* __restrict__ dec_term, const float* __restrict__ enc_term,
              const float* __restrict__ b_fus, float* __restrict__ out) {
  const int bd = blockIdx.x;        // b*128 + d
  const int b  = bd >> 7;
  const int ebase = blockIdx.y * 64;
  const int tid = threadIdx.x;
  const int eo = tid >> 7;          // 0..1
  const int o4 = (tid & 127) << 2;  // 0..508
  const float4 dv = *(const float4*)(dec_term + (size_t)bd * kGrid + o4);
  const float4 bv = *(const float4*)(b_fus + o4);
  const float4 db = make_float4(dv.x + bv.x, dv.y + bv.y, dv.z + bv.z, dv.w + bv.w);
  const float* encb = enc_term + (size_t)b * kE * kGrid;
  float* outb = out + (size_t)bd * kE * kGrid;
#pragma unroll 4
  for (int e0 = 0; e0 < 64; e0 += 2) {
    const int e = ebase + e0 + eo;
    const float4 ev = *(const float4*)(encb + (size_t)e * kGrid + o4);
    const float4 o = make_float4(db.x + ev.x, db.y + ev.y, db.z + ev.z, db.w + ev.w);
    *(float4*)(outb + (size_t)e * kGrid + o4) = o;
  }
}

// 3-tap zero-padded blur of dec_term (axis d) and enc_term (axis e)
__global__ __launch_bounds__(256)
void blur_both(const float* __restrict__ dec_term, const float* __restrict__ enc_term,
               float* __restrict__ dec_blur, float* __restrict__ enc_blur) {
  const int idx = blockIdx.x * 256 + threadIdx.x;
  constexpr int decN = kB * kD * kGrid;  // 262144
  if (idx < decN) {
    const int d = (idx >> 9) & (kD - 1);
    float v = kG1 * dec_term[idx];
    if (d > 0)      v += kG0 * dec_term[idx - kGrid];
    if (d < kD - 1) v += kG0 * dec_term[idx + kGrid];
    dec_blur[idx] = v;
  } else {
    const int j = idx - decN;
    if (j < kB * kE * kGrid) {
      const int e = (j >> 9) & (kE - 1);
      float v = kG1 * enc_term[j];
      if (e > 0)      v += kG0 * enc_term[j - kGrid];
      if (e < kE - 1) v += kG0 * enc_term[j + kGrid];
      enc_blur[j] = v;
    }
  }
}

// blurred[b,d,e,o] = dec_blur[b,d,o]*sE + enc_blur[b,e,o]*sD + b_fus[o]*sE*sD
// mask[b,d,e] = ||blurred||>0 ; one wave per (b,d,e), 4 waves/block
__global__ __launch_bounds__(256)
void mask_kernel(const float* __restrict__ dec_blur, const float* __restrict__ enc_blur,
                 const float* __restrict__ b_fus, float* __restrict__ mask_out) {
  const int bid = blockIdx.x * 4 + (threadIdx.x >> 6);  // (b*kD + d)*kE + e
  const int e = bid & (kE - 1);
  const int d = (bid >> 8) & (kD - 1);
  const int b = bid >> 15;
  const float sE  = (e == 0 || e == kE - 1) ? kEdge : 1.f;
  const float sD  = (d == 0 || d == kD - 1) ? kEdge : 1.f;
  const float sED = sE * sD;
  const int lane = threadIdx.x & 63;
  const float* dp = dec_blur + ((size_t)(b * kD + d)) * kGrid + lane * 8;
  const float* ep = enc_blur + ((size_t)(b * kE + e)) * kGrid + lane * 8;
  const float* zp = b_fus + lane * 8;
  float acc = 0.f;
#pragma unroll
  for (int j = 0; j < 2; ++j) {
    const float4 dv = *(const float4*)(dp + 4 * j);
    const float4 ev = *(const float4*)(ep + 4 * j);
    const float4 zv = *(const float4*)(zp + 4 * j);
    float t;
    t = dv.x * sE + ev.x * sD + zv.x * sED; acc += t * t;
    t = dv.y * sE + ev.y * sD + zv.y * sED; acc += t * t;
    t = dv.z * sE + ev.z * sD + zv.z * sED; acc += t * t;
    t = dv.w * sE + ev.w * sD + zv.w * sED; acc += t * t;
  }
#pragma unroll
  for (int off = 32; off > 0; off >>= 1) acc += __shfl_down(acc, off);
  if (lane == 0) mask_out[bid] = (acc > 0.f) ? 1.f : 0.f;
}

}  // namespace

extern "C" void kernel_launch(void* const* d_in, const int* in_sizes, int n_in,
                              void* d_out, int out_size, void* d_ws, size_t ws_size,
                              hipStream_t stream) {
  const float* enc_h  = (const float*)d_in[0];
  const float* dec_h  = (const float*)d_in[1];
  const float* enc_m  = (const float*)d_in[2];
  const float* dec_m  = (const float*)d_in[3];
  const float* W_enc  = (const float*)d_in[4];
  const float* b_enc  = (const float*)d_in[5];
  const float* W_dec  = (const float*)d_in[6];
  const float* b_dec  = (const float*)d_in[7];
  const float* W_fus  = (const float*)d_in[8];
  const float* b_fus  = (const float*)d_in[9];
  float* out = (float*)d_out;
  float* ws  = (float*)d_ws;

  float* enc_proj = ws;                       // 4*256*512 = 524288
  float* dec_proj = enc_proj + 524288;        // 4*128*512 = 262144
  float* enc_term = dec_proj + 262144;        // 524288
  float* dec_term = enc_term + 524288;        // 262144
  float* enc_blur = dec_term + 262144;        // 524288
  float* dec_blur = enc_blur + 524288;        // 262144
  // total ws use: 2359296 floats = 9.4 MB

  const dim3 blk(256);
  // phase 1: projections (+bias, *mask)
  hipLaunchKernelGGL(gemm_nt, dim3(kGrid / BN, (kB * kE) / BM), blk, 0, stream,
                     enc_h, W_enc, b_enc, enc_m, enc_proj, kHidden, kHidden, kGrid);
  hipLaunchKernelGGL(gemm_nt, dim3(kGrid / BN, (kB * kD) / BM), blk, 0, stream,
                     dec_h, W_dec, b_dec, dec_m, dec_proj, kHidden, kHidden, kGrid);
  // phase 2: fusion terms (no bias/mask; W_fus split columns)
  hipLaunchKernelGGL(gemm_nt, dim3(kGrid / BN, (kB * kE) / BM), blk, 0, stream,
                     enc_proj, W_fus, (const float*)nullptr, (const float*)nullptr,
                     enc_term, kGrid, 2 * kGrid, kGrid);
  hipLaunchKernelGGL(gemm_nt, dim3(kGrid / BN, (kB * kD) / BM), blk, 0, stream,
                     dec_proj, W_fus + kGrid, (const float*)nullptr, (const float*)nullptr,
                     dec_term, kGrid, 2 * kGrid, kGrid);
  // phase 3: 256 MB grid write (2048 blocks: bd x 4 e-chunks)
  hipLaunchKernelGGL(assemble, dim3(kB * kD, kE / 64), blk, 0, stream,
                     dec_term, enc_term, b_fus, out);
  // phase 4: blurs of the two separable components, then mask
  hipLaunchKernelGGL(blur_both, dim3((kB * kD * kGrid + kB * kE * kGrid) / 256), blk, 0, stream,
                     dec_term, enc_term, dec_blur, enc_blur);
  hipLaunchKernelGGL(mask_kernel, dim3(kB * kD * kE / 4), blk, 0, stream,
                     dec_blur, enc_blur, b_fus, out + (size_t)kB * kD * kE * kGrid);
}

// Round 3
// 385.455 us; speedup vs baseline: 1.4655x; 1.4655x over previous
//
#include <hip/hip_runtime.h>

namespace {

constexpr int kGrid = 512;   // O and G
constexpr int kB = 4;
constexpr int kE = 256;
constexpr int kD = 128;
// H = 1024, BE = kB*kE = 1024 rows, BD = kB*kD = 512 rows

// gaussian kernel, KSIZE=3, SIGMA=1
constexpr float kG0   = 0.27406862f;
constexpr float kG1   = 0.45186276f;
constexpr float kEdge = kG0 + kG1;

typedef __attribute__((ext_vector_type(8))) short bf16x8;
typedef __attribute__((ext_vector_type(4))) float f32x4;

__device__ __forceinline__ ushort f2bf(float f) {
  union { float f; uint u; } v{f};
  return (ushort)((v.u + 0x7fffu + ((v.u >> 16) & 1u)) >> 16);  // RNE
}

// ---- prep 1: fp32 -> bf16 for enc_h (1M), dec_h (0.5M), W_fus (0.5M) ----
__global__ __launch_bounds__(256)
void convert_all(const float* __restrict__ enc_h, const float* __restrict__ dec_h,
                 const float* __restrict__ W_fus, ushort* __restrict__ hid,
                 ushort* __restrict__ wfus) {
  const int idx = (blockIdx.x * 256 + threadIdx.x) * 4;
  const float* src; ushort* dst;
  if (idx < 1048576)       { src = enc_h + idx;             dst = hid + idx; }
  else if (idx < 1572864)  { src = dec_h + (idx - 1048576); dst = hid + idx; }
  else                     { src = W_fus + (idx - 1572864); dst = wfus + (idx - 1572864); }
  const float4 v = *(const float4*)src;
  ushort4 o; o.x = f2bf(v.x); o.y = f2bf(v.y); o.z = f2bf(v.z); o.w = f2bf(v.w);
  *(ushort4*)dst = o;
}

// ---- prep 2: transpose+convert W_enc/W_dec [512][1024] -> WT[z][1024][512] bf16 ----
__global__ __launch_bounds__(256)
void transpose_cvt(const float* __restrict__ W_enc, const float* __restrict__ W_dec,
                   ushort* __restrict__ WT) {
  const float* Wsrc = blockIdx.z ? W_dec : W_enc;
  ushort* outT = WT + (size_t)blockIdx.z * 1024 * 512;
  __shared__ ushort Ts[32][36];
  const int h0 = blockIdx.x * 32, g0 = blockIdx.y * 32;
  const int tx = threadIdx.x & 7, ty = threadIdx.x >> 3;   // tx: 8 x float4, ty: 32 rows
  const float4 v = *(const float4*)(Wsrc + (size_t)(g0 + ty) * 1024 + h0 + tx * 4);
  Ts[tx * 4 + 0][ty] = f2bf(v.x); Ts[tx * 4 + 1][ty] = f2bf(v.y);
  Ts[tx * 4 + 2][ty] = f2bf(v.z); Ts[tx * 4 + 3][ty] = f2bf(v.w);
  __syncthreads();
  ushort4 o; o.x = Ts[ty][tx * 4 + 0]; o.y = Ts[ty][tx * 4 + 1];
  o.z = Ts[ty][tx * 4 + 2]; o.w = Ts[ty][tx * 4 + 3];
  *(ushort4*)(outT + (size_t)(h0 + ty) * 512 + g0 + tx * 4) = o;
}

// ---- prep 3: cvec[o]=Wf_e[o,:]@b_enc (o<512), cvec[512+o]=Wf_d[o,:]@b_dec (fp32) ----
__global__ __launch_bounds__(256)
void cvec_kernel(const float* __restrict__ W_fus, const float* __restrict__ b_enc,
                 const float* __restrict__ b_dec, float* __restrict__ cvec) {
  const int wid = blockIdx.x * 4 + (threadIdx.x >> 6);   // 0..1023
  const int lane = threadIdx.x & 63;
  const int sel = wid >> 9, o = wid & 511;
  const float* wrow = W_fus + (size_t)o * 1024 + sel * 512 + lane * 8;
  const float* bv = (sel ? b_dec : b_enc) + lane * 8;
  float s = 0.f;
#pragma unroll
  for (int j = 0; j < 8; ++j) s += wrow[j] * bv[j];
#pragma unroll
  for (int off = 32; off; off >>= 1) s += __shfl_down(s, off);
  if (!lane) cvec[wid] = s;
}

// ---- GEMM core: 64x64 tile, BK=64, 4 waves (2x2 quadrants), mfma 16x16x32 bf16 ----
// A [M][lda] bf16 K-major, B [N][ldb] bf16 K-major; both frags load identically.
// C/D layout (m89): col = lane&15, row = (lane>>4)*4 + q.

// weights GEMM: Mmat[z][o][h] = sum_g wfus[o][z*512+g] * WT[z][h][g], bf16 out
__global__ __launch_bounds__(256)
void gemm_w(const ushort* __restrict__ wfus, const ushort* __restrict__ WT,
            ushort* __restrict__ Mmat) {
  const int z = blockIdx.z;
  const short* A = (const short*)wfus + z * 512;                 // lda=1024
  const short* B = (const short*)WT + (size_t)z * 1024 * 512;    // ldb=512
  ushort* Cw = Mmat + (size_t)z * 512 * 1024;
  __shared__ short As[64][72], Bs[64][72];
  const int tid = threadIdx.x, wid = tid >> 6, lane = tid & 63;
  const int row0 = blockIdx.y * 64, col0 = blockIdx.x * 64;
  const int srow = tid >> 2, sc = tid & 3;
  const short* Ap = A + (size_t)(row0 + srow) * 1024 + sc * 8;
  const short* Bp = B + (size_t)(col0 + srow) * 512 + sc * 8;
  const int wr = (wid >> 1) * 32, wc = (wid & 1) * 32;
  const int r16 = lane & 15, kb = lane >> 4;
  f32x4 acc[2][2] = {};
  for (int k0 = 0; k0 < 512; k0 += 64) {
    const bf16x8 alo = *(const bf16x8*)(Ap + k0);
    const bf16x8 ahi = *(const bf16x8*)(Ap + k0 + 32);
    const bf16x8 blo = *(const bf16x8*)(Bp + k0);
    const bf16x8 bhi = *(const bf16x8*)(Bp + k0 + 32);
    __syncthreads();
    *(bf16x8*)&As[srow][sc * 8] = alo;  *(bf16x8*)&As[srow][(sc + 4) * 8] = ahi;
    *(bf16x8*)&Bs[srow][sc * 8] = blo;  *(bf16x8*)&Bs[srow][(sc + 4) * 8] = bhi;
    __syncthreads();
#pragma unroll
    for (int ks = 0; ks < 2; ++ks) {
      const int ko = ks * 32 + kb * 8;
      const bf16x8 a0 = *(const bf16x8*)&As[wr + r16][ko];
      const bf16x8 a1 = *(const bf16x8*)&As[wr + 16 + r16][ko];
      const bf16x8 b0 = *(const bf16x8*)&Bs[wc + r16][ko];
      const bf16x8 b1 = *(const bf16x8*)&Bs[wc + 16 + r16][ko];
      acc[0][0] = __builtin_amdgcn_mfma_f32_16x16x32_bf16(a0, b0, acc[0][0], 0, 0, 0);
      acc[0][1] = __builtin_amdgcn_mfma_f32_16x16x32_bf16(a0, b1, acc[0][1], 0, 0, 0);
      acc[1][0] = __builtin_amdgcn_mfma_f32_16x16x32_bf16(a1, b0, acc[1][0], 0, 0, 0);
      acc[1][1] = __builtin_amdgcn_mfma_f32_16x16x32_bf16(a1, b1, acc[1][1], 0, 0, 0);
    }
  }
#pragma unroll
  for (int i = 0; i < 2; ++i)
#pragma unroll
    for (int j = 0; j < 2; ++j)
#pragma unroll
      for (int q = 0; q < 4; ++q) {
        const int r = row0 + wr + i * 16 + kb * 4 + q;
        const int c = col0 + wc + j * 16 + r16;
        Cw[(size_t)r * 1024 + c] = f2bf(acc[i][j][q]);
      }
}

// activations GEMM: term[r][o] = mask[r] * (sum_h hid[r][h]*Mmat[z][o][h] + cvec[..o])
// rows 0..1023 = enc (z=0), rows 1024..1535 = dec (z=1); fp32 out
__global__ __launch_bounds__(256)
void gemm_t(const ushort* __restrict__ hid, const ushort* __restrict__ Mmat,
            const float* __restrict__ cvec, const float* __restrict__ enc_mask,
            const float* __restrict__ dec_mask, float* __restrict__ term) {
  const int row0 = blockIdx.y * 64, col0 = blockIdx.x * 64;
  const bool enc = row0 < 1024;
  const short* A = (const short*)hid;                                   // lda=1024
  const short* B = (const short*)Mmat + (enc ? 0 : (size_t)512 * 1024); // ldb=1024
  const float* cv = cvec + (enc ? 0 : 512);
  const float* rmb = enc ? enc_mask : (dec_mask - 1024);
  __shared__ short As[64][72], Bs[64][72];
  const int tid = threadIdx.x, wid = tid >> 6, lane = tid & 63;
  const int srow = tid >> 2, sc = tid & 3;
  const short* Ap = A + (size_t)(row0 + srow) * 1024 + sc * 8;
  const short* Bp = B + (size_t)(col0 + srow) * 1024 + sc * 8;
  const int wr = (wid >> 1) * 32, wc = (wid & 1) * 32;
  const int r16 = lane & 15, kb = lane >> 4;
  f32x4 acc[2][2] = {};
  for (int k0 = 0; k0 < 1024; k0 += 64) {
    const bf16x8 alo = *(const bf16x8*)(Ap + k0);
    const bf16x8 ahi = *(const bf16x8*)(Ap + k0 + 32);
    const bf16x8 blo = *(const bf16x8*)(Bp + k0);
    const bf16x8 bhi = *(const bf16x8*)(Bp + k0 + 32);
    __syncthreads();
    *(bf16x8*)&As[srow][sc * 8] = alo;  *(bf16x8*)&As[srow][(sc + 4) * 8] = ahi;
    *(bf16x8*)&Bs[srow][sc * 8] = blo;  *(bf16x8*)&Bs[srow][(sc + 4) * 8] = bhi;
    __syncthreads();
#pragma unroll
    for (int ks = 0; ks < 2; ++ks) {
      const int ko = ks * 32 + kb * 8;
      const bf16x8 a0 = *(const bf16x8*)&As[wr + r16][ko];
      const bf16x8 a1 = *(const bf16x8*)&As[wr + 16 + r16][ko];
      const bf16x8 b0 = *(const bf16x8*)&Bs[wc + r16][ko];
      const bf16x8 b1 = *(const bf16x8*)&Bs[wc + 16 + r16][ko];
      acc[0][0] = __builtin_amdgcn_mfma_f32_16x16x32_bf16(a0, b0, acc[0][0], 0, 0, 0);
      acc[0][1] = __builtin_amdgcn_mfma_f32_16x16x32_bf16(a0, b1, acc[0][1], 0, 0, 0);
      acc[1][0] = __builtin_amdgcn_mfma_f32_16x16x32_bf16(a1, b0, acc[1][0], 0, 0, 0);
      acc[1][1] = __builtin_amdgcn_mfma_f32_16x16x32_bf16(a1, b1, acc[1][1], 0, 0, 0);
    }
  }
#pragma unroll
  for (int i = 0; i < 2; ++i)
#pragma unroll
    for (int j = 0; j < 2; ++j)
#pragma unroll
      for (int q = 0; q < 4; ++q) {
        const int r = row0 + wr + i * 16 + kb * 4 + q;
        const int c = col0 + wc + j * 16 + r16;
        term[(size_t)r * 512 + c] = (acc[i][j][q] + cv[c]) * rmb[r];
      }
}

// ---- grid assembly: out[b,d,e,o] = dec_term[b,d,o] + enc_term[b,e,o] + b_fus[o] ----
__global__ __launch_bounds__(256)
void assemble(const float* __restrict__ dec_term, const float* __restrict__ enc_term,
              const float* __restrict__ b_fus, float* __restrict__ out) {
  const int bd = blockIdx.x;
  const int b  = bd >> 7;
  const int ebase = blockIdx.y * 64;
  const int tid = threadIdx.x;
  const int eo = tid >> 7;
  const int o4 = (tid & 127) << 2;
  const float4 dv = *(const float4*)(dec_term + (size_t)bd * kGrid + o4);
  const float4 bv = *(const float4*)(b_fus + o4);
  const float4 db = make_float4(dv.x + bv.x, dv.y + bv.y, dv.z + bv.z, dv.w + bv.w);
  const float* encb = enc_term + (size_t)b * kE * kGrid;
  float* outb = out + (size_t)bd * kE * kGrid;
#pragma unroll 4
  for (int e0 = 0; e0 < 64; e0 += 2) {
    const int e = ebase + e0 + eo;
    const float4 ev = *(const float4*)(encb + (size_t)e * kGrid + o4);
    *(float4*)(outb + (size_t)e * kGrid + o4) =
        make_float4(db.x + ev.x, db.y + ev.y, db.z + ev.z, db.w + ev.w);
  }
}

// ---- 3-tap zero-padded blur of dec_term (axis d) and enc_term (axis e) ----
__global__ __launch_bounds__(256)
void blur_both(const float* __restrict__ dec_term, const float* __restrict__ enc_term,
               float* __restrict__ dec_blur, float* __restrict__ enc_blur) {
  const int idx = blockIdx.x * 256 + threadIdx.x;
  constexpr int decN = kB * kD * kGrid;
  if (idx < decN) {
    const int d = (idx >> 9) & (kD - 1);
    float v = kG1 * dec_term[idx];
    if (d > 0)      v += kG0 * dec_term[idx - kGrid];
    if (d < kD - 1) v += kG0 * dec_term[idx + kGrid];
    dec_blur[idx] = v;
  } else {
    const int j = idx - decN;
    if (j < kB * kE * kGrid) {
      const int e = (j >> 9) & (kE - 1);
      float v = kG1 * enc_term[j];
      if (e > 0)      v += kG0 * enc_term[j - kGrid];
      if (e < kE - 1) v += kG0 * enc_term[j + kGrid];
      enc_blur[j] = v;
    }
  }
}

// ---- mask via separability: blurred = dec_blur*sE + enc_blur*sD + b_fus*sE*sD ----
__global__ __launch_bounds__(256)
void mask_kernel(const float* __restrict__ dec_blur, const float* __restrict__ enc_blur,
                 const float* __restrict__ b_fus, float* __restrict__ mask_out) {
  const int bid = blockIdx.x * 4 + (threadIdx.x >> 6);
  const int e = bid & (kE - 1);
  const int d = (bid >> 8) & (kD - 1);
  const int b = bid >> 15;
  const float sE  = (e == 0 || e == kE - 1) ? kEdge : 1.f;
  const float sD  = (d == 0 || d == kD - 1) ? kEdge : 1.f;
  const float sED = sE * sD;
  const int lane = threadIdx.x & 63;
  const float* dp = dec_blur + ((size_t)(b * kD + d)) * kGrid + lane * 8;
  const float* ep = enc_blur + ((size_t)(b * kE + e)) * kGrid + lane * 8;
  const float* zp = b_fus + lane * 8;
  float acc = 0.f;
#pragma unroll
  for (int j = 0; j < 2; ++j) {
    const float4 dv = *(const float4*)(dp + 4 * j);
    const float4 ev = *(const float4*)(ep + 4 * j);
    const float4 zv = *(const float4*)(zp + 4 * j);
    float t;
    t = dv.x * sE + ev.x * sD + zv.x * sED; acc += t * t;
    t = dv.y * sE + ev.y * sD + zv.y * sED; acc += t * t;
    t = dv.z * sE + ev.z * sD + zv.z * sED; acc += t * t;
    t = dv.w * sE + ev.w * sD + zv.w * sED; acc += t * t;
  }
#pragma unroll
  for (int off = 32; off; off >>= 1) acc += __shfl_down(acc, off);
  if (!lane) mask_out[bid] = (acc > 0.f) ? 1.f : 0.f;
}

}  // namespace

extern "C" void kernel_launch(void* const* d_in, const int* in_sizes, int n_in,
                              void* d_out, int out_size, void* d_ws, size_t ws_size,
                              hipStream_t stream) {
  const float* enc_h  = (const float*)d_in[0];
  const float* dec_h  = (const float*)d_in[1];
  const float* enc_m  = (const float*)d_in[2];
  const float* dec_m  = (const float*)d_in[3];
  const float* W_enc  = (const float*)d_in[4];
  const float* b_enc  = (const float*)d_in[5];
  const float* W_dec  = (const float*)d_in[6];
  const float* b_dec  = (const float*)d_in[7];
  const float* W_fus  = (const float*)d_in[8];
  const float* b_fus  = (const float*)d_in[9];
  float* out = (float*)d_out;
  float* ws  = (float*)d_ws;

  // ws layout (floats):
  // term:   [0, 786432)         enc_term rows 0..1023, dec_term rows 1024..1535
  // cvec:   [786432, 787456)
  // bf16 region from 787456 (as ushort): hid 1572864, wfus 524288, WT 1048576, Mmat 1048576
  float* term = ws;
  float* cvec = ws + 786432;
  ushort* hid  = (ushort*)(ws + 787456);
  ushort* wfus = hid + 1572864;
  ushort* WT   = wfus + 524288;
  ushort* Mmat = WT + 1048576;
  float* enc_term = term;
  float* dec_term = term + 524288;
  // blur buffers alias hid (dead after gemm_t): 262144 + 524288 = 786432 floats exactly
  float* dec_blur = (float*)hid;
  float* enc_blur = dec_blur + 262144;

  const dim3 blk(256);
  hipLaunchKernelGGL(convert_all, dim3(2048), blk, 0, stream, enc_h, dec_h, W_fus, hid, wfus);
  hipLaunchKernelGGL(transpose_cvt, dim3(32, 16, 2), blk, 0, stream, W_enc, W_dec, WT);
  hipLaunchKernelGGL(cvec_kernel, dim3(256), blk, 0, stream, W_fus, b_enc, b_dec, cvec);
  hipLaunchKernelGGL(gemm_w, dim3(16, 8, 2), blk, 0, stream, wfus, WT, Mmat);
  hipLaunchKernelGGL(gemm_t, dim3(8, 24), blk, 0, stream, hid, Mmat, cvec, enc_m, dec_m, term);
  hipLaunchKernelGGL(assemble, dim3(kB * kD, kE / 64), blk, 0, stream,
                     dec_term, enc_term, b_fus, out);
  hipLaunchKernelGGL(blur_both, dim3(3072), blk, 0, stream,
                     dec_term, enc_term, dec_blur, enc_blur);
  hipLaunchKernelGGL(mask_kernel, dim3(kB * kD * kE / 4), blk, 0, stream,
                     dec_blur, enc_blur, b_fus, out + (size_t)kB * kD * kE * kGrid);
}